// Round 1
// 958.621 us; speedup vs baseline: 1.0094x; 1.0094x over previous
//
#include <hip/hip_runtime.h>
#include <stdint.h>

typedef unsigned short u16;
typedef uint32_t u32;
typedef short bf16x8 __attribute__((ext_vector_type(8)));
typedef float f32x4 __attribute__((ext_vector_type(4)));

#define DEV_INLINE __device__ __forceinline__

DEV_INLINE float b2f(u16 u) { union { u32 u; float f; } a; a.u = ((u32)u) << 16; return a.f; }
DEV_INLINE u16 f2b(float f) {
    union { float f; u32 u; } a; a.f = f;
    u32 u = a.u;
    u += 0x7fffu + ((u >> 16) & 1u);
    return (u16)(u >> 16);
}

typedef __attribute__((address_space(1))) u32 as1_u32;
typedef __attribute__((address_space(3))) u32 as3_u32;
DEV_INLINE void async16(void* lds, const void* g) {
    __builtin_amdgcn_global_load_lds((as1_u32*)g, (as3_u32*)lds, 16, 0, 0);
}

// ---------------------------------------------------------------------------
// Generic batched bf16 GEMM: C[z] = A[z] (M,K) @ B[z]^T, B stored (N,K) row-major.
// Batch offset = (z>>5)*z?1 + (z&31)*z?2  (elements).
// MODE 0: fp32 store. MODE 1: bf16 store. MODE 2: bf16 store of acc*scale + causal mask.
// CMASK: skip output blocks fully above the diagonal (col0 > row0) + computed causal
//        mask in MODE 2 epilogue (c > r ? -1e9 : 0) -- replaces the fp32 mask read.
// KCAP:  causal K-cap: K-loop only up to t < row0+128 (for probs @ kv GEMM where
//        cols of A beyond the diagonal tile are exactly zero / unwritten).
// Requires: M % 128 == 0 (grid.y = M/128), N % 128 == 0 (grid.x = N/128), K % 32 == 0.
// ---------------------------------------------------------------------------
template <int MODE, bool CMASK = false, bool KCAP = false>
__global__ __launch_bounds__(256) void gemm_bt(
    const u16* __restrict__ Ab, const u16* __restrict__ Bb, void* __restrict__ Cv,
    int K, long lda, long ldb, long ldc,
    long zA1, long zA2, long zB1, long zB2, long zC1, long zC2,
    float scale)
{
    __shared__ __align__(16) u16 As[128 * 32];
    __shared__ __align__(16) u16 Bs[128 * 32];

    const long row0 = (long)blockIdx.y * 128;
    const long col0 = (long)blockIdx.x * 128;
    if (CMASK && col0 > row0) return;  // fully-masked causal block: never read downstream

    const int z = blockIdx.z;
    const long zb = z >> 5, zh = z & 31;
    const u16* A = Ab + zb * zA1 + zh * zA2;
    const u16* B = Bb + zb * zB1 + zh * zB2;

    const int tid = threadIdx.x;
    const int w = tid >> 6, l = tid & 63;
    const int quad = l >> 4, lrow = l & 15;
    const int wm = w & 1, wn = w >> 1;

    f32x4 acc[4][4];
#pragma unroll
    for (int mi = 0; mi < 4; mi++)
#pragma unroll
        for (int ni = 0; ni < 4; ni++) {
            f32x4 zv = {0.f, 0.f, 0.f, 0.f};
            acc[mi][ni] = zv;
        }

    // staging: wave w covers rows w*16 + j*64 (j=0,1); lane l -> row +(l>>2), 16B chunk (l&3)
    const u16* gA = A + (row0 + w * 16 + (l >> 2)) * lda + (l & 3) * 8;
    const u16* gB = B + (col0 + w * 16 + (l >> 2)) * ldb + (l & 3) * 8;
    u16* lA = &As[(w * 16) * 32];
    u16* lB = &Bs[(w * 16) * 32];
    const long a64 = 64 * lda, b64 = 64 * ldb;

    int nk = K >> 5;
    if (KCAP) {
        const int nkc = (int)(row0 >> 5) + 4;  // t < row0+128
        nk = nk < nkc ? nk : nkc;
    }
    for (int kt = 0; kt < nk; ++kt) {
        __syncthreads();
        async16(lA, gA);
        async16(lA + 64 * 32, gA + a64);
        async16(lB, gB);
        async16(lB + 64 * 32, gB + b64);
        gA += 32;
        gB += 32;
        __syncthreads();  // drains vmcnt(0) -> LDS tiles valid

        bf16x8 af[4], bfr[4];
#pragma unroll
        for (int i = 0; i < 4; i++)
            af[i] = *(const bf16x8*)&As[(wm * 64 + i * 16 + lrow) * 32 + quad * 8];
#pragma unroll
        for (int i = 0; i < 4; i++)
            bfr[i] = *(const bf16x8*)&Bs[(wn * 64 + i * 16 + lrow) * 32 + quad * 8];
#pragma unroll
        for (int mi = 0; mi < 4; mi++)
#pragma unroll
            for (int ni = 0; ni < 4; ni++)
                acc[mi][ni] = __builtin_amdgcn_mfma_f32_16x16x32_bf16(af[mi], bfr[ni], acc[mi][ni], 0, 0, 0);
    }

    // epilogue: C/D frag mapping col = lane&15, row = quad*4 + reg
    const long crow = row0 + wm * 64 + quad * 4;
    const long ccol = col0 + wn * 64 + lrow;
    float* Cf = (float*)Cv + zb * zC1 + zh * zC2;
    u16* Cb = (u16*)Cv + zb * zC1 + zh * zC2;
#pragma unroll
    for (int mi = 0; mi < 4; mi++)
#pragma unroll
        for (int rr = 0; rr < 4; rr++) {
            const long r = crow + mi * 16 + rr;
#pragma unroll
            for (int ni = 0; ni < 4; ni++) {
                const long c = ccol + ni * 16;
                const float v = acc[mi][ni][rr];
                if constexpr (MODE == 0) {
                    Cf[r * ldc + c] = v;
                } else if constexpr (MODE == 1) {
                    Cb[r * ldc + c] = f2b(v);
                } else {
                    const float mv = (c > r) ? -1e9f : 0.f;  // computed causal mask
                    Cb[r * ldc + c] = f2b(v * scale + mv);
                }
            }
        }
}

// ---------------------------------------------------------------------------
// transpose + cast to bf16: src (R,C) ldS -> dst (C,R) ldD, batched over z
// ---------------------------------------------------------------------------
DEV_INLINE float ldval(const float* p) { return *p; }
DEV_INLINE float ldval(const u16* p) { return b2f(*p); }

template <typename SRC>
__global__ __launch_bounds__(256) void transpose_b16(
    const SRC* __restrict__ src, u16* __restrict__ dst,
    int R, int C, long ldS, long ldD, long zS, long zD)
{
    __shared__ float t[32][33];
    src += (long)blockIdx.z * zS;
    dst += (long)blockIdx.z * zD;
    const int tx = threadIdx.x & 31, ty = threadIdx.x >> 5;  // ty 0..7
    const long c0 = (long)blockIdx.x * 32, r0 = (long)blockIdx.y * 32;
#pragma unroll
    for (int i = 0; i < 4; i++) {
        long r = r0 + ty + i * 8, c = c0 + tx;
        if (r < R && c < C) t[ty + i * 8][tx] = ldval(&src[r * ldS + c]);
    }
    __syncthreads();
#pragma unroll
    for (int i = 0; i < 4; i++) {
        long c = c0 + ty + i * 8, r = r0 + tx;
        if (r < R && c < C) dst[c * ldD + r] = f2b(t[tx][ty + i * 8]);
    }
}

// row-wise fp32 -> bf16 cast (no transpose), batched
__global__ __launch_bounds__(256) void conv_b16(
    const float* __restrict__ src, u16* __restrict__ dst,
    int C, long ldS, long ldD, long zS, long zD)
{
    const long r = blockIdx.x;
    const float* s = src + (long)blockIdx.z * zS + r * ldS;
    u16* d = dst + (long)blockIdx.z * zD + r * ldD;
    for (int c = threadIdx.x; c < C; c += 256) d[c] = f2b(s[c]);
}

// rmsnorm over C cols of row blockIdx.x (fp32 in, bf16 out)
__global__ __launch_bounds__(256) void rmsnorm_b16(
    const float* __restrict__ X, const float* __restrict__ W, u16* __restrict__ Y,
    int C, long ldx, long ldy)
{
    const long r = blockIdx.x;
    const float* x = X + r * ldx;
    u16* y = Y + r * ldy;
    float ss = 0.f;
    for (int c = threadIdx.x; c < C; c += 256) { float v = x[c]; ss += v * v; }
    for (int off = 32; off; off >>= 1) ss += __shfl_down(ss, off);
    __shared__ float red[4];
    if ((threadIdx.x & 63) == 0) red[threadIdx.x >> 6] = ss;
    __syncthreads();
    const float tot = red[0] + red[1] + red[2] + red[3];
    const float inv = rsqrtf(tot / (float)C + 1e-6f);
    for (int c = threadIdx.x; c < C; c += 256) y[c] = f2b(x[c] * inv * W[c]);
}

// rope for k_pe: kv fp32 (n,640) cols 512..575 -> kcat bf16 (n,576) cols 512..575
__global__ __launch_bounds__(256) void rope_k_kernel(
    const float* __restrict__ kv, const float* __restrict__ fc, u16* __restrict__ kcat)
{
    const int idx = blockIdx.x * 256 + threadIdx.x;  // < 2048*32
    const int n = idx >> 5, i = idx & 31;
    const int s = n & 1023;
    const float e = kv[(long)n * 640 + 512 + 2 * i];
    const float o = kv[(long)n * 640 + 512 + 2 * i + 1];
    const float cs = fc[s * 64 + 2 * i], sn = fc[s * 64 + 2 * i + 1];
    kcat[(long)n * 576 + 512 + 2 * i] = f2b(e * cs - o * sn);
    kcat[(long)n * 576 + 512 + 2 * i + 1] = f2b(e * sn + o * cs);
}

// rope for q_pe: q bf16 (n, h*192+128..191) -> qcat bf16 (n, h*576 + 512..575)
__global__ __launch_bounds__(256) void rope_q_kernel(
    const u16* __restrict__ q, const float* __restrict__ fc, u16* __restrict__ qcat)
{
    const long idx = (long)blockIdx.x * 256 + threadIdx.x;  // < 2048*32*32
    const int i = (int)(idx & 31);
    const long nh = idx >> 5;
    const int h = (int)(nh & 31);
    const long n = nh >> 5;
    const int s = (int)(n & 1023);
    const float e = b2f(q[n * 6144 + h * 192 + 128 + 2 * i]);
    const float o = b2f(q[n * 6144 + h * 192 + 128 + 2 * i + 1]);
    const float cs = fc[s * 64 + 2 * i], sn = fc[s * 64 + 2 * i + 1];
    qcat[n * 18432 + h * 576 + 512 + 2 * i] = f2b(e * cs - o * sn);
    qcat[n * 18432 + h * 576 + 512 + 2 * i + 1] = f2b(e * sn + o * cs);
}

// in-place row softmax, causal-capped: row s only has valid cols [0, kcap),
// kcap = (s & ~127) + 128 (uniform within a 128-row tile; matches s4 block skip
// and s5 K-cap). Cols >= kcap are never written nor read downstream.
__global__ __launch_bounds__(256) void softmax_rows(u16* __restrict__ P)
{
    const long base = (long)blockIdx.x * 1024;
    const int s = blockIdx.x & 1023;
    const int kcap = (s & ~127) + 128;
    const int tid = threadIdx.x;
    __shared__ float red[8];
    float vals[4];
    float m = -3.4e38f;
#pragma unroll
    for (int i = 0; i < 4; i++) {
        const int c = tid + i * 256;
        float v = (c < kcap) ? b2f(P[base + c]) : -3.4e38f;
        vals[i] = v;
        m = fmaxf(m, v);
    }
    for (int off = 32; off; off >>= 1) m = fmaxf(m, __shfl_down(m, off));
    if ((tid & 63) == 0) red[tid >> 6] = m;
    __syncthreads();
    const float m4 = fmaxf(fmaxf(red[0], red[1]), fmaxf(red[2], red[3]));
    float e[4];
    float sum = 0.f;
#pragma unroll
    for (int i = 0; i < 4; i++) {
        e[i] = exp2f((vals[i] - m4) * 1.44269504088896f);
        sum += e[i];
    }
    for (int off = 32; off; off >>= 1) sum += __shfl_down(sum, off);
    if ((tid & 63) == 0) red[4 + (tid >> 6)] = sum;
    __syncthreads();
    const float inv = 1.0f / (red[4] + red[5] + red[6] + red[7]);
#pragma unroll
    for (int i = 0; i < 4; i++) {
        const int c = tid + i * 256;
        if (c < kcap) P[base + c] = f2b(e[i] * inv);
    }
}

__global__ void sentinel_kernel(float* out, float v) { out[0] = v; }

// ---------------------------------------------------------------------------
extern "C" void kernel_launch(void* const* d_in, const int* in_sizes, int n_in,
                              void* d_out, int out_size, void* d_ws, size_t ws_size,
                              hipStream_t stream)
{
    const float* x = (const float*)d_in[0];
    const float* fc = (const float*)d_in[1];
    // d_in[2] (mask) no longer read: causal mask is computed in the s4 epilogue.
    const float* wq_a = (const float*)d_in[3];
    const float* qnw = (const float*)d_in[4];
    const float* wq_b = (const float*)d_in[5];
    const float* wkva = (const float*)d_in[6];
    const float* kvnw = (const float*)d_in[7];
    const float* wkvb = (const float*)d_in[8];
    const float* wo = (const float*)d_in[9];
    float* out = (float*)d_out;

    // ---- workspace layout (bytes): ws_size = 268,435,456 (256 MiB, measured R0).
    // Peak plan = 251,920,384 B.
    //   persist:  [0, 39,845,888)  wkbv | wo_t | kvn_t
    //   kcat:     [39,845,888, 42,205,184)
    //   qcat:     [42,205,184, 117,702,656)   ... o1 overlays after s4
    //   scores:   [117,702,656, 251,920,384)  ... early buffers + o2 overlay
    const size_t NEED = 251920384ULL;
    if (ws_size < NEED) {
        sentinel_kernel<<<1, 1, 0, stream>>>(out, (float)ws_size);
        return;
    }
    char* ws = (char*)d_ws;
    u16* wkbv   = (u16*)(ws + 0);            // (32,128,512)   4,194,304
    u16* wo_t   = (u16*)(ws + 4194304);      // (4096,4096)   33,554,432
    u16* kvn_t  = (u16*)(ws + 37748736);     // (2,512,1024)   2,097,152
    u16* kcat   = (u16*)(ws + 39845888);     // (2048,576)     2,359,296
    u16* qcat   = (u16*)(ws + 42205184);     // (2048,32,576) 75,497,472  live s3..s4
    u16* o1     = (u16*)(ws + 42205184);     // (2048,32,512) overlays qcat (dead after s4)
    u16* scores = (u16*)(ws + 117702656);    // (2,32,1024,1024) 134,217,728  live s4..s5
    // early buffers (all dead before s4) overlay the scores region:
    u16*   xb     = (u16*)(ws + 117702656);  // (2048,4096)   16,777,216
    u16*   wq_a_t = (u16*)(ws + 134479872);  // (1536,4096)   12,582,912
    u16*   wq_b_t = (u16*)(ws + 147062784);  // (6144,1536)   18,874,368
    u16*   wkva_t = (u16*)(ws + 165937152);  // (640,4096)     5,242,880  rows 576..639 pad
    u16*   wkbn_t = (u16*)(ws + 171180032);  // (32,512,128)   4,194,304
    float* q_lat  = (float*)(ws + 175374336);// (2048,1536)   12,582,912
    float* kvf    = (float*)(ws + 187957248);// (2048,640)     5,242,880
    u16*   qn     = (u16*)(ws + 193200128);  // (2048,1536)    6,291,456
    u16*   q      = (u16*)(ws + 199491584);  // (2048,6144)   25,165,824 -> ends 224,657,408
    u16*   o2     = (u16*)(ws + 117702656);  // (2048,4096) overlays scores (dead after s5)

    const dim3 blk(256);
    const float SCALE = 0.0721687836487032f;  // 192^-0.5

    // ---- weight prep: transpose/cast to bf16 (N,K) row-major ----
    transpose_b16<float><<<dim3(48, 128, 1), blk, 0, stream>>>(wq_a, wq_a_t, 4096, 1536, 1536, 4096, 0, 0);
    transpose_b16<float><<<dim3(192, 48, 1), blk, 0, stream>>>(wq_b, wq_b_t, 1536, 6144, 6144, 1536, 0, 0);
    transpose_b16<float><<<dim3(18, 128, 1), blk, 0, stream>>>(wkva, wkva_t, 4096, 576, 576, 4096, 0, 0);
    transpose_b16<float><<<dim3(16, 4, 32), blk, 0, stream>>>(wkvb, wkbn_t, 128, 512, 512, 128, 256 * 512, 512 * 128);
    conv_b16<<<dim3(128, 1, 32), blk, 0, stream>>>(wkvb + 128 * 512, wkbv, 512, 512, 512, 256 * 512, 128 * 512);
    transpose_b16<float><<<dim3(128, 128, 1), blk, 0, stream>>>(wo, wo_t, 4096, 4096, 4096, 4096, 0, 0);
    conv_b16<<<dim3(2048, 1, 1), blk, 0, stream>>>(x, xb, 4096, 4096, 4096, 0, 0);

    // ---- s1a: q_lat = xb @ wq_a^T : (2048,1536) fp32 ----
    gemm_bt<0><<<dim3(12, 16, 1), blk, 0, stream>>>(xb, wq_a_t, q_lat, 4096, 4096, 4096, 1536,
                                                    0, 0, 0, 0, 0, 0, 1.f);
    // ---- s1b: kvf = xb @ wkv_a^T : (2048,640) fp32 (cols 576..639 garbage) ----
    gemm_bt<0><<<dim3(5, 16, 1), blk, 0, stream>>>(xb, wkva_t, kvf, 4096, 4096, 4096, 640,
                                                   0, 0, 0, 0, 0, 0, 1.f);
    // ---- norms + rope_k + kv transpose ----
    rmsnorm_b16<<<2048, blk, 0, stream>>>(q_lat, qnw, qn, 1536, 1536, 1536);
    rmsnorm_b16<<<2048, blk, 0, stream>>>(kvf, kvnw, kcat, 512, 640, 576);
    rope_k_kernel<<<256, blk, 0, stream>>>(kvf, fc, kcat);
    transpose_b16<u16><<<dim3(16, 32, 2), blk, 0, stream>>>(kcat, kvn_t, 1024, 512, 576, 1024,
                                                            (long)1024 * 576, (long)512 * 1024);
    // ---- s2: q = qn @ wq_b^T : (2048,6144) bf16 ----
    gemm_bt<1><<<dim3(48, 16, 1), blk, 0, stream>>>(qn, wq_b_t, q, 1536, 1536, 1536, 6144,
                                                    0, 0, 0, 0, 0, 0, 1.f);
    // ---- s3: qcat[:, :512] = q_nope @ wkv_b_nope^T per head (z = h) ----
    gemm_bt<1><<<dim3(4, 16, 32), blk, 0, stream>>>(q, wkbn_t, qcat, 128, 6144, 128, 18432,
                                                    0, 192, 0, (long)512 * 128, 0, 576, 1.f);
    // ---- rope_q -> qcat[:, 512:576] ----
    rope_q_kernel<<<8192, blk, 0, stream>>>(q, fc, qcat);
    // ---- s4: scores = (qcat @ kcat^T)*SCALE + causal mask, per (b,h), z = b*32+h ----
    //      CMASK: skip blocks above the diagonal (28/64) + computed mask (no fp32 mask fetch)
    gemm_bt<2, true><<<dim3(8, 8, 64), blk, 0, stream>>>(qcat, kcat, scores, 576, 18432, 576, 1024,
                                                         (long)1024 * 18432, 576, (long)1024 * 576, 0,
                                                         (long)32 * 1048576, 1048576, SCALE);
    // ---- softmax in place (causal-capped cols) ----
    softmax_rows<<<65536, blk, 0, stream>>>(scores);
    // ---- s5: o1[b,s,h,:] = probs @ kv_n (via kvn_t), K capped at row0+128 ----
    gemm_bt<1, false, true><<<dim3(4, 8, 64), blk, 0, stream>>>(scores, kvn_t, o1, 1024, 1024, 1024, 16384,
                                                                (long)32 * 1048576, 1048576, (long)512 * 1024, 0,
                                                                (long)1024 * 16384, 512, 1.f);
    // ---- s6: o2[n, h*128+d] = o1 @ wkv_b_v^T per head (z = h) ----
    gemm_bt<1><<<dim3(1, 16, 32), blk, 0, stream>>>(o1, wkbv, o2, 512, 16384, 512, 4096,
                                                    0, 512, 0, (long)128 * 512, 0, 128, 1.f);
    // ---- s7: out = o2 @ wo^T : (2048,4096) fp32 ----
    gemm_bt<0><<<dim3(32, 16, 1), blk, 0, stream>>>(o2, wo_t, out, 4096, 4096, 4096, 4096,
                                                    0, 0, 0, 0, 0, 0, 1.f);
    (void)in_sizes; (void)n_in; (void)out_size; (void)d_in;
}

// Round 2
// 955.267 us; speedup vs baseline: 1.0130x; 1.0035x over previous
//
#include <hip/hip_runtime.h>
#include <stdint.h>

typedef unsigned short u16;
typedef uint32_t u32;
typedef short bf16x8 __attribute__((ext_vector_type(8)));
typedef float f32x4 __attribute__((ext_vector_type(4)));

#define DEV_INLINE __device__ __forceinline__

DEV_INLINE float b2f(u16 u) { union { u32 u; float f; } a; a.u = ((u32)u) << 16; return a.f; }
DEV_INLINE u16 f2b(float f) {
    union { float f; u32 u; } a; a.f = f;
    u32 u = a.u;
    u += 0x7fffu + ((u >> 16) & 1u);
    return (u16)(u >> 16);
}

typedef __attribute__((address_space(1))) u32 as1_u32;
typedef __attribute__((address_space(3))) u32 as3_u32;
DEV_INLINE void async16(void* lds, const void* g) {
    __builtin_amdgcn_global_load_lds((as1_u32*)g, (as3_u32*)lds, 16, 0, 0);
}

// ---------------------------------------------------------------------------
// Generic batched bf16 GEMM: C[z] = A[z] (M,K) @ B[z]^T, B stored (N,K) row-major.
// Batch offset = (z>>5)*z?1 + (z&31)*z?2  (elements).
// MODE 0: fp32 store. MODE 1: bf16 store. MODE 2: bf16 store of acc*scale + causal mask.
// CMASK: skip output blocks fully above the diagonal (col0 > row0) + computed causal
//        mask in MODE 2 epilogue (c > r ? -1e9 : 0).
// KCAP:  causal K-cap: K-loop only up to t < row0+128.
// Requires: M % 128 == 0 (grid.y = M/128), N % 128 == 0 (grid.x = N/128), K % 32 == 0.
// ---------------------------------------------------------------------------
template <int MODE, bool CMASK = false, bool KCAP = false>
__global__ __launch_bounds__(256) void gemm_bt(
    const u16* __restrict__ Ab, const u16* __restrict__ Bb, void* __restrict__ Cv,
    int K, long lda, long ldb, long ldc,
    long zA1, long zA2, long zB1, long zB2, long zC1, long zC2,
    float scale)
{
    __shared__ __align__(16) u16 As[128 * 32];
    __shared__ __align__(16) u16 Bs[128 * 32];

    const long row0 = (long)blockIdx.y * 128;
    const long col0 = (long)blockIdx.x * 128;
    if (CMASK && col0 > row0) return;  // fully-masked causal block: never read downstream

    const int z = blockIdx.z;
    const long zb = z >> 5, zh = z & 31;
    const u16* A = Ab + zb * zA1 + zh * zA2;
    const u16* B = Bb + zb * zB1 + zh * zB2;

    const int tid = threadIdx.x;
    const int w = tid >> 6, l = tid & 63;
    const int quad = l >> 4, lrow = l & 15;
    const int wm = w & 1, wn = w >> 1;

    f32x4 acc[4][4];
#pragma unroll
    for (int mi = 0; mi < 4; mi++)
#pragma unroll
        for (int ni = 0; ni < 4; ni++) {
            f32x4 zv = {0.f, 0.f, 0.f, 0.f};
            acc[mi][ni] = zv;
        }

    // staging: wave w covers rows w*16 + j*64 (j=0,1); lane l -> row +(l>>2), 16B chunk (l&3)
    const u16* gA = A + (row0 + w * 16 + (l >> 2)) * lda + (l & 3) * 8;
    const u16* gB = B + (col0 + w * 16 + (l >> 2)) * ldb + (l & 3) * 8;
    u16* lA = &As[(w * 16) * 32];
    u16* lB = &Bs[(w * 16) * 32];
    const long a64 = 64 * lda, b64 = 64 * ldb;

    int nk = K >> 5;
    if (KCAP) {
        const int nkc = (int)(row0 >> 5) + 4;  // t < row0+128
        nk = nk < nkc ? nk : nkc;
    }
    for (int kt = 0; kt < nk; ++kt) {
        __syncthreads();
        async16(lA, gA);
        async16(lA + 64 * 32, gA + a64);
        async16(lB, gB);
        async16(lB + 64 * 32, gB + b64);
        gA += 32;
        gB += 32;
        __syncthreads();  // drains vmcnt(0) -> LDS tiles valid

        bf16x8 af[4], bfr[4];
#pragma unroll
        for (int i = 0; i < 4; i++)
            af[i] = *(const bf16x8*)&As[(wm * 64 + i * 16 + lrow) * 32 + quad * 8];
#pragma unroll
        for (int i = 0; i < 4; i++)
            bfr[i] = *(const bf16x8*)&Bs[(wn * 64 + i * 16 + lrow) * 32 + quad * 8];
#pragma unroll
        for (int mi = 0; mi < 4; mi++)
#pragma unroll
            for (int ni = 0; ni < 4; ni++)
                acc[mi][ni] = __builtin_amdgcn_mfma_f32_16x16x32_bf16(af[mi], bfr[ni], acc[mi][ni], 0, 0, 0);
    }

    // epilogue: C/D frag mapping col = lane&15, row = quad*4 + reg
    const long crow = row0 + wm * 64 + quad * 4;
    const long ccol = col0 + wn * 64 + lrow;
    float* Cf = (float*)Cv + zb * zC1 + zh * zC2;
    u16* Cb = (u16*)Cv + zb * zC1 + zh * zC2;
#pragma unroll
    for (int mi = 0; mi < 4; mi++)
#pragma unroll
        for (int rr = 0; rr < 4; rr++) {
            const long r = crow + mi * 16 + rr;
#pragma unroll
            for (int ni = 0; ni < 4; ni++) {
                const long c = ccol + ni * 16;
                const float v = acc[mi][ni][rr];
                if constexpr (MODE == 0) {
                    Cf[r * ldc + c] = v;
                } else if constexpr (MODE == 1) {
                    Cb[r * ldc + c] = f2b(v);
                } else {
                    const float mv = (c > r) ? -1e9f : 0.f;  // computed causal mask
                    Cb[r * ldc + c] = f2b(v * scale + mv);
                }
            }
        }
}

// ---------------------------------------------------------------------------
// transpose + cast to bf16: src (R,C) ldS -> dst (C,R) ldD, batched over z
// ---------------------------------------------------------------------------
DEV_INLINE float ldval(const float* p) { return *p; }
DEV_INLINE float ldval(const u16* p) { return b2f(*p); }

template <typename SRC>
__global__ __launch_bounds__(256) void transpose_b16(
    const SRC* __restrict__ src, u16* __restrict__ dst,
    int R, int C, long ldS, long ldD, long zS, long zD)
{
    __shared__ float t[32][33];
    src += (long)blockIdx.z * zS;
    dst += (long)blockIdx.z * zD;
    const int tx = threadIdx.x & 31, ty = threadIdx.x >> 5;  // ty 0..7
    const long c0 = (long)blockIdx.x * 32, r0 = (long)blockIdx.y * 32;
#pragma unroll
    for (int i = 0; i < 4; i++) {
        long r = r0 + ty + i * 8, c = c0 + tx;
        if (r < R && c < C) t[ty + i * 8][tx] = ldval(&src[r * ldS + c]);
    }
    __syncthreads();
#pragma unroll
    for (int i = 0; i < 4; i++) {
        long c = c0 + ty + i * 8, r = r0 + tx;
        if (r < R && c < C) dst[c * ldD + r] = f2b(t[tx][ty + i * 8]);
    }
}

// row-wise fp32 -> bf16 cast (no transpose), batched
__global__ __launch_bounds__(256) void conv_b16(
    const float* __restrict__ src, u16* __restrict__ dst,
    int C, long ldS, long ldD, long zS, long zD)
{
    const long r = blockIdx.x;
    const float* s = src + (long)blockIdx.z * zS + r * ldS;
    u16* d = dst + (long)blockIdx.z * zD + r * ldD;
    for (int c = threadIdx.x; c < C; c += 256) d[c] = f2b(s[c]);
}

// rmsnorm over C cols of row blockIdx.x (fp32 in, bf16 out)
__global__ __launch_bounds__(256) void rmsnorm_b16(
    const float* __restrict__ X, const float* __restrict__ W, u16* __restrict__ Y,
    int C, long ldx, long ldy)
{
    const long r = blockIdx.x;
    const float* x = X + r * ldx;
    u16* y = Y + r * ldy;
    float ss = 0.f;
    for (int c = threadIdx.x; c < C; c += 256) { float v = x[c]; ss += v * v; }
    for (int off = 32; off; off >>= 1) ss += __shfl_down(ss, off);
    __shared__ float red[4];
    if ((threadIdx.x & 63) == 0) red[threadIdx.x >> 6] = ss;
    __syncthreads();
    const float tot = red[0] + red[1] + red[2] + red[3];
    const float inv = rsqrtf(tot / (float)C + 1e-6f);
    for (int c = threadIdx.x; c < C; c += 256) y[c] = f2b(x[c] * inv * W[c]);
}

// rope for k_pe: kv fp32 (n,640) cols 512..575 -> kcat bf16 (n,576) cols 512..575
__global__ __launch_bounds__(256) void rope_k_kernel(
    const float* __restrict__ kv, const float* __restrict__ fc, u16* __restrict__ kcat)
{
    const int idx = blockIdx.x * 256 + threadIdx.x;  // < 2048*32
    const int n = idx >> 5, i = idx & 31;
    const int s = n & 1023;
    const float e = kv[(long)n * 640 + 512 + 2 * i];
    const float o = kv[(long)n * 640 + 512 + 2 * i + 1];
    const float cs = fc[s * 64 + 2 * i], sn = fc[s * 64 + 2 * i + 1];
    kcat[(long)n * 576 + 512 + 2 * i] = f2b(e * cs - o * sn);
    kcat[(long)n * 576 + 512 + 2 * i + 1] = f2b(e * sn + o * cs);
}

// rope for q_pe: q bf16 (n, h*192+128..191) -> qcat2 bf16 [h][n][576] cols 512..575
__global__ __launch_bounds__(256) void rope_q_kernel(
    const u16* __restrict__ q, const float* __restrict__ fc, u16* __restrict__ qcat)
{
    const long idx = (long)blockIdx.x * 256 + threadIdx.x;  // < 2048*32*32
    const int i = (int)(idx & 31);
    const long nh = idx >> 5;
    const int h = (int)(nh & 31);
    const long n = nh >> 5;
    const int s = (int)(n & 1023);
    const float e = b2f(q[n * 6144 + h * 192 + 128 + 2 * i]);
    const float o = b2f(q[n * 6144 + h * 192 + 128 + 2 * i + 1]);
    const float cs = fc[s * 64 + 2 * i], sn = fc[s * 64 + 2 * i + 1];
    u16* dst = qcat + ((long)h * 2048 + n) * 576 + 512 + 2 * i;
    dst[0] = f2b(e * cs - o * sn);
    dst[1] = f2b(e * sn + o * cs);
}

// in-place row softmax, causal-capped: row s only has valid cols [0, kcap),
// kcap = (s & ~127) + 128 (uniform within a 128-row tile; matches s4 block skip
// and s5 K-cap). Cols >= kcap are never written nor read downstream.
__global__ __launch_bounds__(256) void softmax_rows(u16* __restrict__ P)
{
    const long base = (long)blockIdx.x * 1024;
    const int s = blockIdx.x & 1023;
    const int kcap = (s & ~127) + 128;
    const int tid = threadIdx.x;
    __shared__ float red[8];
    float vals[4];
    float m = -3.4e38f;
#pragma unroll
    for (int i = 0; i < 4; i++) {
        const int c = tid + i * 256;
        float v = (c < kcap) ? b2f(P[base + c]) : -3.4e38f;
        vals[i] = v;
        m = fmaxf(m, v);
    }
    for (int off = 32; off; off >>= 1) m = fmaxf(m, __shfl_down(m, off));
    if ((tid & 63) == 0) red[tid >> 6] = m;
    __syncthreads();
    const float m4 = fmaxf(fmaxf(red[0], red[1]), fmaxf(red[2], red[3]));
    float e[4];
    float sum = 0.f;
#pragma unroll
    for (int i = 0; i < 4; i++) {
        e[i] = exp2f((vals[i] - m4) * 1.44269504088896f);
        sum += e[i];
    }
    for (int off = 32; off; off >>= 1) sum += __shfl_down(sum, off);
    if ((tid & 63) == 0) red[4 + (tid >> 6)] = sum;
    __syncthreads();
    const float inv = 1.0f / (red[4] + red[5] + red[6] + red[7]);
#pragma unroll
    for (int i = 0; i < 4; i++) {
        const int c = tid + i * 256;
        if (c < kcap) P[base + c] = f2b(e[i] * inv);
    }
}

__global__ void sentinel_kernel(float* out, float v) { out[0] = v; }

// ---------------------------------------------------------------------------
extern "C" void kernel_launch(void* const* d_in, const int* in_sizes, int n_in,
                              void* d_out, int out_size, void* d_ws, size_t ws_size,
                              hipStream_t stream)
{
    const float* x = (const float*)d_in[0];
    const float* fc = (const float*)d_in[1];
    // d_in[2] (mask) no longer read: causal mask is computed in the s4 epilogue.
    const float* wq_a = (const float*)d_in[3];
    const float* qnw = (const float*)d_in[4];
    const float* wq_b = (const float*)d_in[5];
    const float* wkva = (const float*)d_in[6];
    const float* kvnw = (const float*)d_in[7];
    const float* wkvb = (const float*)d_in[8];
    const float* wo = (const float*)d_in[9];
    float* out = (float*)d_out;

    // ---- workspace layout (bytes): ws_size = 268,435,456 (256 MiB).
    // Peak plan = 251,920,384 B.
    //   persist:  [0, 39,845,888)  wkbv | wo_t | kvn_t
    //   kcat:     [39,845,888, 42,205,184)
    //   qcat:     [42,205,184, 117,702,656)  HEAD-MAJOR [h][n][576] ... o1 overlays after s4
    //   scores:   [117,702,656, 251,920,384)  ... early buffers + o2 overlay
    const size_t NEED = 251920384ULL;
    if (ws_size < NEED) {
        sentinel_kernel<<<1, 1, 0, stream>>>(out, (float)ws_size);
        return;
    }
    char* ws = (char*)d_ws;
    u16* wkbv   = (u16*)(ws + 0);            // (32,128,512)   4,194,304
    u16* wo_t   = (u16*)(ws + 4194304);      // (4096,4096)   33,554,432
    u16* kvn_t  = (u16*)(ws + 37748736);     // (2,512,1024)   2,097,152
    u16* kcat   = (u16*)(ws + 39845888);     // (2048,576)     2,359,296
    u16* qcat   = (u16*)(ws + 42205184);     // [32 h][2048 n][576] 75,497,472  live s3..s4
    u16* o1     = (u16*)(ws + 42205184);     // [32 h][2048 n][512] overlays qcat (dead after s4)
    u16* scores = (u16*)(ws + 117702656);    // (2,32,1024,1024) 134,217,728  live s4..s5
    // early buffers (all dead before s4) overlay the scores region:
    u16*   xb     = (u16*)(ws + 117702656);  // (2048,4096)   16,777,216
    u16*   wq_a_t = (u16*)(ws + 134479872);  // (1536,4096)   12,582,912
    u16*   wq_b_t = (u16*)(ws + 147062784);  // (6144,1536)   18,874,368
    u16*   wkva_t = (u16*)(ws + 165937152);  // (640,4096)     5,242,880  rows 576..639 pad
    u16*   wkbn_t = (u16*)(ws + 171180032);  // (32,512,128)   4,194,304
    float* q_lat  = (float*)(ws + 175374336);// (2048,1536)   12,582,912
    float* kvf    = (float*)(ws + 187957248);// (2048,640)     5,242,880
    u16*   qn     = (u16*)(ws + 193200128);  // (2048,1536)    6,291,456
    u16*   q      = (u16*)(ws + 199491584);  // (2048,6144)   25,165,824 -> ends 224,657,408
    u16*   o2     = (u16*)(ws + 117702656);  // (2048,4096) overlays scores (dead after s5)

    const dim3 blk(256);
    const float SCALE = 0.0721687836487032f;  // 192^-0.5

    // ---- weight prep: transpose/cast to bf16 (N,K) row-major ----
    transpose_b16<float><<<dim3(48, 128, 1), blk, 0, stream>>>(wq_a, wq_a_t, 4096, 1536, 1536, 4096, 0, 0);
    transpose_b16<float><<<dim3(192, 48, 1), blk, 0, stream>>>(wq_b, wq_b_t, 1536, 6144, 6144, 1536, 0, 0);
    transpose_b16<float><<<dim3(18, 128, 1), blk, 0, stream>>>(wkva, wkva_t, 4096, 576, 576, 4096, 0, 0);
    transpose_b16<float><<<dim3(16, 4, 32), blk, 0, stream>>>(wkvb, wkbn_t, 128, 512, 512, 128, 256 * 512, 512 * 128);
    conv_b16<<<dim3(128, 1, 32), blk, 0, stream>>>(wkvb + 128 * 512, wkbv, 512, 512, 512, 256 * 512, 128 * 512);
    transpose_b16<float><<<dim3(128, 128, 1), blk, 0, stream>>>(wo, wo_t, 4096, 4096, 4096, 4096, 0, 0);
    conv_b16<<<dim3(2048, 1, 1), blk, 0, stream>>>(x, xb, 4096, 4096, 4096, 0, 0);

    // ---- s1a: q_lat = xb @ wq_a^T : (2048,1536) fp32 ----
    gemm_bt<0><<<dim3(12, 16, 1), blk, 0, stream>>>(xb, wq_a_t, q_lat, 4096, 4096, 4096, 1536,
                                                    0, 0, 0, 0, 0, 0, 1.f);
    // ---- s1b: kvf = xb @ wkv_a^T : (2048,640) fp32 (cols 576..639 garbage) ----
    gemm_bt<0><<<dim3(5, 16, 1), blk, 0, stream>>>(xb, wkva_t, kvf, 4096, 4096, 4096, 640,
                                                   0, 0, 0, 0, 0, 0, 1.f);
    // ---- norms + rope_k + kv transpose ----
    rmsnorm_b16<<<2048, blk, 0, stream>>>(q_lat, qnw, qn, 1536, 1536, 1536);
    rmsnorm_b16<<<2048, blk, 0, stream>>>(kvf, kvnw, kcat, 512, 640, 576);
    rope_k_kernel<<<256, blk, 0, stream>>>(kvf, fc, kcat);
    transpose_b16<u16><<<dim3(16, 32, 2), blk, 0, stream>>>(kcat, kvn_t, 1024, 512, 576, 1024,
                                                            (long)1024 * 576, (long)512 * 1024);
    // ---- s2: q = qn @ wq_b^T : (2048,6144) bf16 ----
    gemm_bt<1><<<dim3(48, 16, 1), blk, 0, stream>>>(qn, wq_b_t, q, 1536, 1536, 1536, 6144,
                                                    0, 0, 0, 0, 0, 0, 1.f);
    // ---- s3: qcat[h][:, :512] = q_nope @ wkv_b_nope^T per head (z = h), head-major out ----
    gemm_bt<1><<<dim3(4, 16, 32), blk, 0, stream>>>(q, wkbn_t, qcat, 128, 6144, 128, 576,
                                                    0, 192, 0, (long)512 * 128, 0, (long)2048 * 576, 1.f);
    // ---- rope_q -> qcat[h][:, 512:576] ----
    rope_q_kernel<<<8192, blk, 0, stream>>>(q, fc, qcat);
    // ---- s4: scores = (qcat @ kcat^T)*SCALE + causal mask, per (b,h), z = b*32+h ----
    //      A head-major: contiguous per z (lda=576). CMASK skips above-diagonal blocks.
    gemm_bt<2, true><<<dim3(8, 8, 64), blk, 0, stream>>>(qcat, kcat, scores, 576, 576, 576, 1024,
                                                         (long)1024 * 576, (long)2048 * 576,
                                                         (long)1024 * 576, 0,
                                                         (long)32 * 1048576, 1048576, SCALE);
    // ---- softmax in place (causal-capped cols) ----
    softmax_rows<<<65536, blk, 0, stream>>>(scores);
    // ---- s5: o1[h][b*1024+s][:] = probs @ kv_n (via kvn_t), K capped at row0+128 ----
    gemm_bt<1, false, true><<<dim3(4, 8, 64), blk, 0, stream>>>(scores, kvn_t, o1, 1024, 1024, 1024, 512,
                                                                (long)32 * 1048576, 1048576, (long)512 * 1024, 0,
                                                                (long)1024 * 512, (long)2048 * 512, 1.f);
    // ---- s6: o2[n, h*128+d] = o1 @ wkv_b_v^T per head (z = h), head-major A ----
    gemm_bt<1><<<dim3(1, 16, 32), blk, 0, stream>>>(o1, wkbv, o2, 512, 512, 512, 4096,
                                                    0, (long)2048 * 512, 0, (long)128 * 512, 0, 128, 1.f);
    // ---- s7: out = o2 @ wo^T : (2048,4096) fp32 ----
    gemm_bt<0><<<dim3(32, 16, 1), blk, 0, stream>>>(o2, wo_t, out, 4096, 4096, 4096, 4096,
                                                    0, 0, 0, 0, 0, 0, 1.f);
    (void)in_sizes; (void)n_in; (void)out_size; (void)d_in;
}

// Round 3
// 750.629 us; speedup vs baseline: 1.2891x; 1.2726x over previous
//
#include <hip/hip_runtime.h>
#include <stdint.h>

typedef unsigned short u16;
typedef uint32_t u32;
typedef short bf16x8 __attribute__((ext_vector_type(8)));
typedef float f32x4 __attribute__((ext_vector_type(4)));

#define DEV_INLINE __device__ __forceinline__

DEV_INLINE float b2f(u16 u) { union { u32 u; float f; } a; a.u = ((u32)u) << 16; return a.f; }
DEV_INLINE u16 f2b(float f) {
    union { float f; u32 u; } a; a.f = f;
    u32 u = a.u;
    u += 0x7fffu + ((u >> 16) & 1u);
    return (u16)(u >> 16);
}

typedef __attribute__((address_space(1))) u32 as1_u32;
typedef __attribute__((address_space(3))) u32 as3_u32;
DEV_INLINE void async16(void* lds, const void* g) {
    __builtin_amdgcn_global_load_lds((as1_u32*)g, (as3_u32*)lds, 16, 0, 0);
}

// ---------------------------------------------------------------------------
// Generic batched bf16 GEMM: C[z] = A[z] (M,K) @ B[z]^T, B stored (N,K) row-major.
// Batch offset = (z>>5)*z?1 + (z&31)*z?2  (elements).
// MODE 0: fp32 store. MODE 1: bf16 store. MODE 2: bf16 store of acc*scale + causal mask.
// CMASK: skip output blocks fully above the diagonal + computed causal mask in MODE 2.
// KCAP:  causal K-cap: K-loop only up to t < row0+128.
// SWZ:   XCD-aware bijective block swizzle (m204): consecutive logical blocks (which
//        share the A row-panel, x-fastest) land on the same XCD -> A panel hits L2
//        instead of being refetched by 8 XCDs.
// Double-buffered LDS (T3 minimum 2-phase): stage tile t+1 before computing tile t;
// ONE __syncthreads per K-step (implied vmcnt(0)+lgkmcnt(0) drain makes it race-free).
// Requires: M % 128 == 0 (grid.y = M/128), N % 128 == 0 (grid.x = N/128), K % 32 == 0.
// ---------------------------------------------------------------------------
template <int MODE, bool CMASK = false, bool KCAP = false, bool SWZ = false>
__global__ __launch_bounds__(256) void gemm_bt(
    const u16* __restrict__ Ab, const u16* __restrict__ Bb, void* __restrict__ Cv,
    int K, long lda, long ldb, long ldc,
    long zA1, long zA2, long zB1, long zB2, long zC1, long zC2,
    float scale)
{
    __shared__ __align__(16) u16 As[2][128 * 32];
    __shared__ __align__(16) u16 Bs[2][128 * 32];

    int bx = blockIdx.x, by = blockIdx.y, bz = blockIdx.z;
    if (SWZ) {
        const int gx = gridDim.x, gy = gridDim.y;
        const int nwg = gx * gy * (int)gridDim.z;
        const int lin = bx + gx * (by + gy * bz);
        const int q = nwg >> 3, r = nwg & 7;
        const int xcd = lin & 7, idx = lin >> 3;
        const int wg = (xcd < r ? xcd * (q + 1) : r * (q + 1) + (xcd - r) * q) + idx;
        bx = wg % gx;
        const int t = wg / gx;
        by = t % gy;
        bz = t / gy;
    }

    const long row0 = (long)by * 128;
    const long col0 = (long)bx * 128;
    if (CMASK && col0 > row0) return;  // fully-masked causal block: never read downstream

    const long zb = bz >> 5, zh = bz & 31;
    const u16* A = Ab + zb * zA1 + zh * zA2;
    const u16* B = Bb + zb * zB1 + zh * zB2;

    const int tid = threadIdx.x;
    const int w = tid >> 6, l = tid & 63;
    const int quad = l >> 4, lrow = l & 15;
    const int wm = w & 1, wn = w >> 1;

    f32x4 acc[4][4];
#pragma unroll
    for (int mi = 0; mi < 4; mi++)
#pragma unroll
        for (int ni = 0; ni < 4; ni++) {
            f32x4 zv = {0.f, 0.f, 0.f, 0.f};
            acc[mi][ni] = zv;
        }

    // staging: wave w covers rows w*16 + j*64 (j=0,1); lane l -> row +(l>>2), 16B chunk (l&3)
    const u16* gA = A + (row0 + w * 16 + (l >> 2)) * lda + (l & 3) * 8;
    const u16* gB = B + (col0 + w * 16 + (l >> 2)) * ldb + (l & 3) * 8;
    const int lofs = (w * 16) * 32;
    const long a64 = 64 * lda, b64 = 64 * ldb;

    int nk = K >> 5;
    if (KCAP) {
        const int nkc = (int)(row0 >> 5) + 4;  // t < row0+128
        nk = nk < nkc ? nk : nkc;
    }

    // prologue: stage tile 0 into buffer 0
    async16(&As[0][lofs], gA);
    async16(&As[0][lofs + 64 * 32], gA + a64);
    async16(&Bs[0][lofs], gB);
    async16(&Bs[0][lofs + 64 * 32], gB + b64);
    gA += 32;
    gB += 32;

    int cur = 0;
    for (int kt = 0; kt < nk; ++kt) {
        __syncthreads();  // implied vmcnt(0): buf[cur] staged; lgkmcnt(0): buf[cur^1] reads done
        if (kt + 1 < nk) {
            const int nxt = cur ^ 1;
            async16(&As[nxt][lofs], gA);
            async16(&As[nxt][lofs + 64 * 32], gA + a64);
            async16(&Bs[nxt][lofs], gB);
            async16(&Bs[nxt][lofs + 64 * 32], gB + b64);
            gA += 32;
            gB += 32;
        }
        bf16x8 af[4], bfr[4];
#pragma unroll
        for (int i = 0; i < 4; i++)
            af[i] = *(const bf16x8*)&As[cur][(wm * 64 + i * 16 + lrow) * 32 + quad * 8];
#pragma unroll
        for (int i = 0; i < 4; i++)
            bfr[i] = *(const bf16x8*)&Bs[cur][(wn * 64 + i * 16 + lrow) * 32 + quad * 8];
#pragma unroll
        for (int mi = 0; mi < 4; mi++)
#pragma unroll
            for (int ni = 0; ni < 4; ni++)
                acc[mi][ni] = __builtin_amdgcn_mfma_f32_16x16x32_bf16(af[mi], bfr[ni], acc[mi][ni], 0, 0, 0);
        cur ^= 1;
    }

    // epilogue: C/D frag mapping col = lane&15, row = quad*4 + reg
    const long crow = row0 + wm * 64 + quad * 4;
    const long ccol = col0 + wn * 64 + lrow;
    float* Cf = (float*)Cv + zb * zC1 + zh * zC2;
    u16* Cb = (u16*)Cv + zb * zC1 + zh * zC2;
#pragma unroll
    for (int mi = 0; mi < 4; mi++)
#pragma unroll
        for (int rr = 0; rr < 4; rr++) {
            const long r = crow + mi * 16 + rr;
#pragma unroll
            for (int ni = 0; ni < 4; ni++) {
                const long c = ccol + ni * 16;
                const float v = acc[mi][ni][rr];
                if constexpr (MODE == 0) {
                    Cf[r * ldc + c] = v;
                } else if constexpr (MODE == 1) {
                    Cb[r * ldc + c] = f2b(v);
                } else {
                    const float mv = (c > r) ? -1e9f : 0.f;  // computed causal mask
                    Cb[r * ldc + c] = f2b(v * scale + mv);
                }
            }
        }
}

// ---------------------------------------------------------------------------
// transpose + cast to bf16: src (R,C) ldS -> dst (C,R) ldD, batched over z
// ---------------------------------------------------------------------------
DEV_INLINE float ldval(const float* p) { return *p; }
DEV_INLINE float ldval(const u16* p) { return b2f(*p); }

template <typename SRC>
__global__ __launch_bounds__(256) void transpose_b16(
    const SRC* __restrict__ src, u16* __restrict__ dst,
    int R, int C, long ldS, long ldD, long zS, long zD)
{
    __shared__ float t[32][33];
    src += (long)blockIdx.z * zS;
    dst += (long)blockIdx.z * zD;
    const int tx = threadIdx.x & 31, ty = threadIdx.x >> 5;  // ty 0..7
    const long c0 = (long)blockIdx.x * 32, r0 = (long)blockIdx.y * 32;
#pragma unroll
    for (int i = 0; i < 4; i++) {
        long r = r0 + ty + i * 8, c = c0 + tx;
        if (r < R && c < C) t[ty + i * 8][tx] = ldval(&src[r * ldS + c]);
    }
    __syncthreads();
#pragma unroll
    for (int i = 0; i < 4; i++) {
        long c = c0 + ty + i * 8, r = r0 + tx;
        if (r < R && c < C) dst[c * ldD + r] = f2b(t[tx][ty + i * 8]);
    }
}

// row-wise fp32 -> bf16 cast (no transpose), batched
__global__ __launch_bounds__(256) void conv_b16(
    const float* __restrict__ src, u16* __restrict__ dst,
    int C, long ldS, long ldD, long zS, long zD)
{
    const long r = blockIdx.x;
    const float* s = src + (long)blockIdx.z * zS + r * ldS;
    u16* d = dst + (long)blockIdx.z * zD + r * ldD;
    for (int c = threadIdx.x; c < C; c += 256) d[c] = f2b(s[c]);
}

// rmsnorm over C cols of row blockIdx.x (fp32 in, bf16 out)
__global__ __launch_bounds__(256) void rmsnorm_b16(
    const float* __restrict__ X, const float* __restrict__ W, u16* __restrict__ Y,
    int C, long ldx, long ldy)
{
    const long r = blockIdx.x;
    const float* x = X + r * ldx;
    u16* y = Y + r * ldy;
    float ss = 0.f;
    for (int c = threadIdx.x; c < C; c += 256) { float v = x[c]; ss += v * v; }
    for (int off = 32; off; off >>= 1) ss += __shfl_down(ss, off);
    __shared__ float red[4];
    if ((threadIdx.x & 63) == 0) red[threadIdx.x >> 6] = ss;
    __syncthreads();
    const float tot = red[0] + red[1] + red[2] + red[3];
    const float inv = rsqrtf(tot / (float)C + 1e-6f);
    for (int c = threadIdx.x; c < C; c += 256) y[c] = f2b(x[c] * inv * W[c]);
}

// rope for k_pe: qk_lat fp32 (n,2176) cols 2048..2111 -> kcat bf16 (n,576) cols 512..575
__global__ __launch_bounds__(256) void rope_k_kernel(
    const float* __restrict__ kv, const float* __restrict__ fc, u16* __restrict__ kcat)
{
    const int idx = blockIdx.x * 256 + threadIdx.x;  // < 2048*32
    const int n = idx >> 5, i = idx & 31;
    const int s = n & 1023;
    const float e = kv[(long)n * 2176 + 2048 + 2 * i];
    const float o = kv[(long)n * 2176 + 2048 + 2 * i + 1];
    const float cs = fc[s * 64 + 2 * i], sn = fc[s * 64 + 2 * i + 1];
    kcat[(long)n * 576 + 512 + 2 * i] = f2b(e * cs - o * sn);
    kcat[(long)n * 576 + 512 + 2 * i + 1] = f2b(e * sn + o * cs);
}

// rope for q_pe: q bf16 (n, h*192+128..191) -> qcat bf16 [h][n][576] cols 512..575
__global__ __launch_bounds__(256) void rope_q_kernel(
    const u16* __restrict__ q, const float* __restrict__ fc, u16* __restrict__ qcat)
{
    const long idx = (long)blockIdx.x * 256 + threadIdx.x;  // < 2048*32*32
    const int i = (int)(idx & 31);
    const long nh = idx >> 5;
    const int h = (int)(nh & 31);
    const long n = nh >> 5;
    const int s = (int)(n & 1023);
    const float e = b2f(q[n * 6144 + h * 192 + 128 + 2 * i]);
    const float o = b2f(q[n * 6144 + h * 192 + 128 + 2 * i + 1]);
    const float cs = fc[s * 64 + 2 * i], sn = fc[s * 64 + 2 * i + 1];
    u16* dst = qcat + ((long)h * 2048 + n) * 576 + 512 + 2 * i;
    dst[0] = f2b(e * cs - o * sn);
    dst[1] = f2b(e * sn + o * cs);
}

// in-place row softmax, causal-capped: row s only has valid cols [0, kcap),
// kcap = (s & ~127) + 128 (uniform within a 128-row tile; matches s4 block skip
// and s5 K-cap). Cols >= kcap are never written nor read downstream.
__global__ __launch_bounds__(256) void softmax_rows(u16* __restrict__ P)
{
    const long base = (long)blockIdx.x * 1024;
    const int s = blockIdx.x & 1023;
    const int kcap = (s & ~127) + 128;
    const int tid = threadIdx.x;
    __shared__ float red[8];
    float vals[4];
    float m = -3.4e38f;
#pragma unroll
    for (int i = 0; i < 4; i++) {
        const int c = tid + i * 256;
        float v = (c < kcap) ? b2f(P[base + c]) : -3.4e38f;
        vals[i] = v;
        m = fmaxf(m, v);
    }
    for (int off = 32; off; off >>= 1) m = fmaxf(m, __shfl_down(m, off));
    if ((tid & 63) == 0) red[tid >> 6] = m;
    __syncthreads();
    const float m4 = fmaxf(fmaxf(red[0], red[1]), fmaxf(red[2], red[3]));
    float e[4];
    float sum = 0.f;
#pragma unroll
    for (int i = 0; i < 4; i++) {
        e[i] = exp2f((vals[i] - m4) * 1.44269504088896f);
        sum += e[i];
    }
    for (int off = 32; off; off >>= 1) sum += __shfl_down(sum, off);
    if ((tid & 63) == 0) red[4 + (tid >> 6)] = sum;
    __syncthreads();
    const float inv = 1.0f / (red[4] + red[5] + red[6] + red[7]);
#pragma unroll
    for (int i = 0; i < 4; i++) {
        const int c = tid + i * 256;
        if (c < kcap) P[base + c] = f2b(e[i] * inv);
    }
}

__global__ void sentinel_kernel(float* out, float v) { out[0] = v; }

// ---------------------------------------------------------------------------
extern "C" void kernel_launch(void* const* d_in, const int* in_sizes, int n_in,
                              void* d_out, int out_size, void* d_ws, size_t ws_size,
                              hipStream_t stream)
{
    const float* x = (const float*)d_in[0];
    const float* fc = (const float*)d_in[1];
    // d_in[2] (mask) no longer read: causal mask is computed in the s4 epilogue.
    const float* wq_a = (const float*)d_in[3];
    const float* qnw = (const float*)d_in[4];
    const float* wq_b = (const float*)d_in[5];
    const float* wkva = (const float*)d_in[6];
    const float* kvnw = (const float*)d_in[7];
    const float* wkvb = (const float*)d_in[8];
    const float* wo = (const float*)d_in[9];
    float* out = (float*)d_out;

    // ---- workspace layout (bytes): ws_size = 268,435,456 (256 MiB).
    // Peak plan = 251,920,384 B.
    //   persist:  [0, 39,845,888)  wkbv | wo_t | kvn_t
    //   kcat:     [39,845,888, 42,205,184)
    //   qcat:     [42,205,184, 117,702,656)  HEAD-MAJOR [h][n][576] ... o1 overlays after s4
    //   scores:   [117,702,656, 251,920,384)  ... early buffers + o2 overlay
    const size_t NEED = 251920384ULL;
    if (ws_size < NEED) {
        sentinel_kernel<<<1, 1, 0, stream>>>(out, (float)ws_size);
        return;
    }
    char* ws = (char*)d_ws;
    u16* wkbv   = (u16*)(ws + 0);            // (32,128,512)   4,194,304
    u16* wo_t   = (u16*)(ws + 4194304);      // (4096,4096)   33,554,432
    u16* kvn_t  = (u16*)(ws + 37748736);     // (2,512,1024)   2,097,152
    u16* kcat   = (u16*)(ws + 39845888);     // (2048,576)     2,359,296
    u16* qcat   = (u16*)(ws + 42205184);     // [32 h][2048 n][576] 75,497,472  live s3..s4
    u16* o1     = (u16*)(ws + 42205184);     // [32 h][2048 n][512] overlays qcat (dead after s4)
    u16* scores = (u16*)(ws + 117702656);    // (2,32,1024,1024) 134,217,728  live s4..s5
    // early buffers (all dead before s4) overlay the scores region:
    u16*   xb     = (u16*)(ws + 117702656);  // (2048,4096)       16,777,216
    u16*   wqkv_t = (u16*)(ws + 134479872);  // (2176,4096)       17,825,792  rows 0..1535=wq_a^T,
                                             //   1536..2111=wkv_a^T, 2112..2175 pad (unread)
    u16*   wq_b_t = (u16*)(ws + 152305664);  // (6144,1536)       18,874,368
    u16*   wkbn_t = (u16*)(ws + 171180032);  // (32,512,128)       4,194,304
    float* qk_lat = (float*)(ws + 175374336);// (2048,2176)       17,825,792  cols 0..1535 q_lat,
                                             //   1536..2047 c_kv, 2048..2111 k_pe raw
    u16*   qn     = (u16*)(ws + 193200128);  // (2048,1536)        6,291,456
    u16*   q      = (u16*)(ws + 199491584);  // (2048,6144)       25,165,824 -> ends 224,657,408
    u16*   o2     = (u16*)(ws + 117702656);  // (2048,4096) overlays scores (dead after s5)

    const dim3 blk(256);
    const float SCALE = 0.0721687836487032f;  // 192^-0.5

    // ---- weight prep: transpose/cast to bf16 (N,K) row-major ----
    transpose_b16<float><<<dim3(48, 128, 1), blk, 0, stream>>>(wq_a, wqkv_t, 4096, 1536, 1536, 4096, 0, 0);
    transpose_b16<float><<<dim3(18, 128, 1), blk, 0, stream>>>(wkva, wqkv_t + (long)1536 * 4096, 4096, 576, 576, 4096, 0, 0);
    transpose_b16<float><<<dim3(192, 48, 1), blk, 0, stream>>>(wq_b, wq_b_t, 1536, 6144, 6144, 1536, 0, 0);
    transpose_b16<float><<<dim3(16, 4, 32), blk, 0, stream>>>(wkvb, wkbn_t, 128, 512, 512, 128, 256 * 512, 512 * 128);
    conv_b16<<<dim3(128, 1, 32), blk, 0, stream>>>(wkvb + 128 * 512, wkbv, 512, 512, 512, 256 * 512, 128 * 512);
    transpose_b16<float><<<dim3(128, 128, 1), blk, 0, stream>>>(wo, wo_t, 4096, 4096, 4096, 4096, 0, 0);
    conv_b16<<<dim3(2048, 1, 1), blk, 0, stream>>>(x, xb, 4096, 4096, 4096, 0, 0);

    // ---- s1 (fused s1a+s1b): qk_lat = xb @ [wq_a | wkv_a]^T : (2048,2176) fp32 ----
    gemm_bt<0, false, false, true><<<dim3(17, 16, 1), blk, 0, stream>>>(
        xb, wqkv_t, qk_lat, 4096, 4096, 4096, 2176, 0, 0, 0, 0, 0, 0, 1.f);
    // ---- norms + rope_k + kv transpose ----
    rmsnorm_b16<<<2048, blk, 0, stream>>>(qk_lat, qnw, qn, 1536, 2176, 1536);
    rmsnorm_b16<<<2048, blk, 0, stream>>>(qk_lat + 1536, kvnw, kcat, 512, 2176, 576);
    rope_k_kernel<<<256, blk, 0, stream>>>(qk_lat, fc, kcat);
    transpose_b16<u16><<<dim3(16, 32, 2), blk, 0, stream>>>(kcat, kvn_t, 1024, 512, 576, 1024,
                                                            (long)1024 * 576, (long)512 * 1024);
    // ---- s2: q = qn @ wq_b^T : (2048,6144) bf16 ----
    gemm_bt<1, false, false, true><<<dim3(48, 16, 1), blk, 0, stream>>>(
        qn, wq_b_t, q, 1536, 1536, 1536, 6144, 0, 0, 0, 0, 0, 0, 1.f);
    // ---- s3: qcat[h][:, :512] = q_nope @ wkv_b_nope^T per head (z = h), head-major out ----
    gemm_bt<1><<<dim3(4, 16, 32), blk, 0, stream>>>(q, wkbn_t, qcat, 128, 6144, 128, 576,
                                                    0, 192, 0, (long)512 * 128, 0, (long)2048 * 576, 1.f);
    // ---- rope_q -> qcat[h][:, 512:576] ----
    rope_q_kernel<<<8192, blk, 0, stream>>>(q, fc, qcat);
    // ---- s4: scores = (qcat @ kcat^T)*SCALE + causal mask, per (b,h), z = b*32+h ----
    gemm_bt<2, true, false, true><<<dim3(8, 8, 64), blk, 0, stream>>>(
        qcat, kcat, scores, 576, 576, 576, 1024,
        (long)1024 * 576, (long)2048 * 576, (long)1024 * 576, 0,
        (long)32 * 1048576, 1048576, SCALE);
    // ---- softmax in place (causal-capped cols) ----
    softmax_rows<<<65536, blk, 0, stream>>>(scores);
    // ---- s5: o1[h][b*1024+s][:] = probs @ kv_n (via kvn_t), K capped at row0+128 ----
    gemm_bt<1, false, true, true><<<dim3(4, 8, 64), blk, 0, stream>>>(
        scores, kvn_t, o1, 1024, 1024, 1024, 512,
        (long)32 * 1048576, 1048576, (long)512 * 1024, 0,
        (long)1024 * 512, (long)2048 * 512, 1.f);
    // ---- s6: o2[n, h*128+d] = o1 @ wkv_b_v^T per head (z = h), head-major A ----
    gemm_bt<1><<<dim3(1, 16, 32), blk, 0, stream>>>(o1, wkbv, o2, 512, 512, 512, 4096,
                                                    0, (long)2048 * 512, 0, (long)128 * 512, 0, 128, 1.f);
    // ---- s7: out = o2 @ wo^T : (2048,4096) fp32 ----
    gemm_bt<0, false, false, true><<<dim3(32, 16, 1), blk, 0, stream>>>(
        o2, wo_t, out, 4096, 4096, 4096, 4096, 0, 0, 0, 0, 0, 0, 1.f);
    (void)in_sizes; (void)n_in; (void)out_size; (void)d_in;
}

// Round 4
// 712.937 us; speedup vs baseline: 1.3573x; 1.0529x over previous
//
#include <hip/hip_runtime.h>
#include <stdint.h>

typedef unsigned short u16;
typedef uint32_t u32;
typedef short bf16x8 __attribute__((ext_vector_type(8)));
typedef float f32x4 __attribute__((ext_vector_type(4)));

#define DEV_INLINE __device__ __forceinline__

DEV_INLINE float b2f(u16 u) { union { u32 u; float f; } a; a.u = ((u32)u) << 16; return a.f; }
DEV_INLINE u16 f2b(float f) {
    union { float f; u32 u; } a; a.f = f;
    u32 u = a.u;
    u += 0x7fffu + ((u >> 16) & 1u);
    return (u16)(u >> 16);
}

typedef __attribute__((address_space(1))) u32 as1_u32;
typedef __attribute__((address_space(3))) u32 as3_u32;
DEV_INLINE void async16(void* lds, const void* g) {
    __builtin_amdgcn_global_load_lds((as1_u32*)g, (as3_u32*)lds, 16, 0, 0);
}

// ---------------------------------------------------------------------------
// Generic batched bf16 GEMM: C[z] = A[z] (M,K) @ B[z]^T, B stored (N,K) row-major.
// Batch offset = (z>>5)*z?1 + (z&31)*z?2  (elements).
// MODE 0: fp32 store. MODE 1: bf16 store. MODE 2: bf16 store of exp2((acc*scale+mask)*log2e)
//         (UNNORMALIZED softmax numerator; causal mask folded: above-diag -> exp -> 0).
// CMASK: skip output blocks fully above the diagonal (for MODE 2 epilogue + block skip).
// KCAP:  causal K-cap: K-loop only up to t < row0+128.
// SWZ:   XCD-aware bijective block swizzle (m204).
// RSC:   MODE-1 epilogue multiplies row r by rowinv[z*1024+r] (softmax denominator).
// Double-buffered LDS (T3 minimum 2-phase): stage tile t+1 before computing tile t;
// ONE __syncthreads per K-step (implied vmcnt(0)+lgkmcnt(0) drain makes it race-free).
// Requires: M % 128 == 0 (grid.y = M/128), N % 128 == 0 (grid.x = N/128), K % 32 == 0.
// ---------------------------------------------------------------------------
template <int MODE, bool CMASK = false, bool KCAP = false, bool SWZ = false, bool RSC = false>
__global__ __launch_bounds__(256) void gemm_bt(
    const u16* __restrict__ Ab, const u16* __restrict__ Bb, void* __restrict__ Cv,
    int K, long lda, long ldb, long ldc,
    long zA1, long zA2, long zB1, long zB2, long zC1, long zC2,
    float scale, const float* __restrict__ rowinv)
{
    __shared__ __align__(16) u16 As[2][128 * 32];
    __shared__ __align__(16) u16 Bs[2][128 * 32];

    int bx = blockIdx.x, by = blockIdx.y, bz = blockIdx.z;
    if (SWZ) {
        const int gx = gridDim.x, gy = gridDim.y;
        const int nwg = gx * gy * (int)gridDim.z;
        const int lin = bx + gx * (by + gy * bz);
        const int q = nwg >> 3, r = nwg & 7;
        const int xcd = lin & 7, idx = lin >> 3;
        const int wg = (xcd < r ? xcd * (q + 1) : r * (q + 1) + (xcd - r) * q) + idx;
        bx = wg % gx;
        const int t = wg / gx;
        by = t % gy;
        bz = t / gy;
    }

    const long row0 = (long)by * 128;
    const long col0 = (long)bx * 128;
    if (CMASK && col0 > row0) return;  // fully-masked causal block: never read downstream

    const long zb = bz >> 5, zh = bz & 31;
    const u16* A = Ab + zb * zA1 + zh * zA2;
    const u16* B = Bb + zb * zB1 + zh * zB2;

    const int tid = threadIdx.x;
    const int w = tid >> 6, l = tid & 63;
    const int quad = l >> 4, lrow = l & 15;
    const int wm = w & 1, wn = w >> 1;

    f32x4 acc[4][4];
#pragma unroll
    for (int mi = 0; mi < 4; mi++)
#pragma unroll
        for (int ni = 0; ni < 4; ni++) {
            f32x4 zv = {0.f, 0.f, 0.f, 0.f};
            acc[mi][ni] = zv;
        }

    // staging: wave w covers rows w*16 + j*64 (j=0,1); lane l -> row +(l>>2), 16B chunk (l&3)
    const u16* gA = A + (row0 + w * 16 + (l >> 2)) * lda + (l & 3) * 8;
    const u16* gB = B + (col0 + w * 16 + (l >> 2)) * ldb + (l & 3) * 8;
    const int lofs = (w * 16) * 32;
    const long a64 = 64 * lda, b64 = 64 * ldb;

    int nk = K >> 5;
    if (KCAP) {
        const int nkc = (int)(row0 >> 5) + 4;  // t < row0+128
        nk = nk < nkc ? nk : nkc;
    }

    // prologue: stage tile 0 into buffer 0
    async16(&As[0][lofs], gA);
    async16(&As[0][lofs + 64 * 32], gA + a64);
    async16(&Bs[0][lofs], gB);
    async16(&Bs[0][lofs + 64 * 32], gB + b64);
    gA += 32;
    gB += 32;

    int cur = 0;
    for (int kt = 0; kt < nk; ++kt) {
        __syncthreads();  // implied vmcnt(0): buf[cur] staged; lgkmcnt(0): buf[cur^1] reads done
        if (kt + 1 < nk) {
            const int nxt = cur ^ 1;
            async16(&As[nxt][lofs], gA);
            async16(&As[nxt][lofs + 64 * 32], gA + a64);
            async16(&Bs[nxt][lofs], gB);
            async16(&Bs[nxt][lofs + 64 * 32], gB + b64);
            gA += 32;
            gB += 32;
        }
        bf16x8 af[4], bfr[4];
#pragma unroll
        for (int i = 0; i < 4; i++)
            af[i] = *(const bf16x8*)&As[cur][(wm * 64 + i * 16 + lrow) * 32 + quad * 8];
#pragma unroll
        for (int i = 0; i < 4; i++)
            bfr[i] = *(const bf16x8*)&Bs[cur][(wn * 64 + i * 16 + lrow) * 32 + quad * 8];
#pragma unroll
        for (int mi = 0; mi < 4; mi++)
#pragma unroll
            for (int ni = 0; ni < 4; ni++)
                acc[mi][ni] = __builtin_amdgcn_mfma_f32_16x16x32_bf16(af[mi], bfr[ni], acc[mi][ni], 0, 0, 0);
        cur ^= 1;
    }

    // epilogue: C/D frag mapping col = lane&15, row = quad*4 + reg
    const long crow = row0 + wm * 64 + quad * 4;
    const long ccol = col0 + wn * 64 + lrow;
    float* Cf = (float*)Cv + zb * zC1 + zh * zC2;
    u16* Cb = (u16*)Cv + zb * zC1 + zh * zC2;
    const float lse = scale * 1.44269504088896f;  // MODE 2: exp2 scale
#pragma unroll
    for (int mi = 0; mi < 4; mi++)
#pragma unroll
        for (int rr = 0; rr < 4; rr++) {
            const long r = crow + mi * 16 + rr;
            float rs = 1.f;
            if (RSC) rs = rowinv[(long)bz * 1024 + r];
#pragma unroll
            for (int ni = 0; ni < 4; ni++) {
                const long c = ccol + ni * 16;
                const float v = acc[mi][ni][rr];
                if constexpr (MODE == 0) {
                    Cf[r * ldc + c] = v;
                } else if constexpr (MODE == 1) {
                    Cb[r * ldc + c] = f2b(RSC ? v * rs : v);
                } else {
                    // unnormalized softmax numerator; above-diag -> exp2(-inf) = 0
                    const float arg = (c > r) ? -1e30f : v * lse;
                    Cb[r * ldc + c] = f2b(exp2f(arg));
                }
            }
        }
}

// ---------------------------------------------------------------------------
// transpose + cast to bf16: src (R,C) ldS -> dst (C,R) ldD, batched over z
// ---------------------------------------------------------------------------
DEV_INLINE float ldval(const float* p) { return *p; }
DEV_INLINE float ldval(const u16* p) { return b2f(*p); }

template <typename SRC>
__global__ __launch_bounds__(256) void transpose_b16(
    const SRC* __restrict__ src, u16* __restrict__ dst,
    int R, int C, long ldS, long ldD, long zS, long zD)
{
    __shared__ float t[32][33];
    src += (long)blockIdx.z * zS;
    dst += (long)blockIdx.z * zD;
    const int tx = threadIdx.x & 31, ty = threadIdx.x >> 5;  // ty 0..7
    const long c0 = (long)blockIdx.x * 32, r0 = (long)blockIdx.y * 32;
#pragma unroll
    for (int i = 0; i < 4; i++) {
        long r = r0 + ty + i * 8, c = c0 + tx;
        if (r < R && c < C) t[ty + i * 8][tx] = ldval(&src[r * ldS + c]);
    }
    __syncthreads();
#pragma unroll
    for (int i = 0; i < 4; i++) {
        long c = c0 + ty + i * 8, r = r0 + tx;
        if (r < R && c < C) dst[c * ldD + r] = f2b(t[tx][ty + i * 8]);
    }
}

// row-wise fp32 -> bf16 cast (no transpose), batched
__global__ __launch_bounds__(256) void conv_b16(
    const float* __restrict__ src, u16* __restrict__ dst,
    int C, long ldS, long ldD, long zS, long zD)
{
    const long r = blockIdx.x;
    const float* s = src + (long)blockIdx.z * zS + r * ldS;
    u16* d = dst + (long)blockIdx.z * zD + r * ldD;
    for (int c = threadIdx.x; c < C; c += 256) d[c] = f2b(s[c]);
}

// rmsnorm over C cols of row blockIdx.x (fp32 in, bf16 out)
__global__ __launch_bounds__(256) void rmsnorm_b16(
    const float* __restrict__ X, const float* __restrict__ W, u16* __restrict__ Y,
    int C, long ldx, long ldy)
{
    const long r = blockIdx.x;
    const float* x = X + r * ldx;
    u16* y = Y + r * ldy;
    float ss = 0.f;
    for (int c = threadIdx.x; c < C; c += 256) { float v = x[c]; ss += v * v; }
    for (int off = 32; off; off >>= 1) ss += __shfl_down(ss, off);
    __shared__ float red[4];
    if ((threadIdx.x & 63) == 0) red[threadIdx.x >> 6] = ss;
    __syncthreads();
    const float tot = red[0] + red[1] + red[2] + red[3];
    const float inv = rsqrtf(tot / (float)C + 1e-6f);
    for (int c = threadIdx.x; c < C; c += 256) y[c] = f2b(x[c] * inv * W[c]);
}

// rope for k_pe: qk_lat fp32 (n,2176) cols 2048..2111 -> kcat bf16 (n,576) cols 512..575
__global__ __launch_bounds__(256) void rope_k_kernel(
    const float* __restrict__ kv, const float* __restrict__ fc, u16* __restrict__ kcat)
{
    const int idx = blockIdx.x * 256 + threadIdx.x;  // < 2048*32
    const int n = idx >> 5, i = idx & 31;
    const int s = n & 1023;
    const float e = kv[(long)n * 2176 + 2048 + 2 * i];
    const float o = kv[(long)n * 2176 + 2048 + 2 * i + 1];
    const float cs = fc[s * 64 + 2 * i], sn = fc[s * 64 + 2 * i + 1];
    kcat[(long)n * 576 + 512 + 2 * i] = f2b(e * cs - o * sn);
    kcat[(long)n * 576 + 512 + 2 * i + 1] = f2b(e * sn + o * cs);
}

// rope for q_pe: q bf16 (n, h*192+128..191) -> qcat bf16 [h][n][576] cols 512..575
__global__ __launch_bounds__(256) void rope_q_kernel(
    const u16* __restrict__ q, const float* __restrict__ fc, u16* __restrict__ qcat)
{
    const long idx = (long)blockIdx.x * 256 + threadIdx.x;  // < 2048*32*32
    const int i = (int)(idx & 31);
    const long nh = idx >> 5;
    const int h = (int)(nh & 31);
    const long n = nh >> 5;
    const int s = (int)(n & 1023);
    const float e = b2f(q[n * 6144 + h * 192 + 128 + 2 * i]);
    const float o = b2f(q[n * 6144 + h * 192 + 128 + 2 * i + 1]);
    const float cs = fc[s * 64 + 2 * i], sn = fc[s * 64 + 2 * i + 1];
    u16* dst = qcat + ((long)h * 2048 + n) * 576 + 512 + 2 * i;
    dst[0] = f2b(e * cs - o * sn);
    dst[1] = f2b(e * sn + o * cs);
}

// row sums of unnormalized P~ (exp'd scores) -> inv[z][r] = 1/sum.
// grid (8, 64): blockIdx.x = 128-row tile, blockIdx.y = z. Valid cols [0, kcap).
__global__ __launch_bounds__(256) void rowsum_inv(
    const u16* __restrict__ P, float* __restrict__ inv)
{
    const int zt = blockIdx.y;
    const int row0 = blockIdx.x * 128;
    const int kcap = row0 + 128;
    const int t = threadIdx.x;
    const int r = t >> 1, half = t & 1;
    const u16* p = P + (long)zt * 1048576 + (long)(row0 + r) * 1024;
    float s = 0.f;
    for (int c = half * 8; c < kcap; c += 16) {
        bf16x8 v = *(const bf16x8*)&p[c];
#pragma unroll
        for (int j = 0; j < 8; j++) s += b2f((u16)v[j]);
    }
    s += __shfl_xor(s, 1);
    if (!half) inv[(long)zt * 1024 + row0 + r] = 1.0f / s;
}

__global__ void sentinel_kernel(float* out, float v) { out[0] = v; }

// ---------------------------------------------------------------------------
extern "C" void kernel_launch(void* const* d_in, const int* in_sizes, int n_in,
                              void* d_out, int out_size, void* d_ws, size_t ws_size,
                              hipStream_t stream)
{
    const float* x = (const float*)d_in[0];
    const float* fc = (const float*)d_in[1];
    // d_in[2] (mask) no longer read: causal mask is computed in the s4 epilogue.
    const float* wq_a = (const float*)d_in[3];
    const float* qnw = (const float*)d_in[4];
    const float* wq_b = (const float*)d_in[5];
    const float* wkva = (const float*)d_in[6];
    const float* kvnw = (const float*)d_in[7];
    const float* wkvb = (const float*)d_in[8];
    const float* wo = (const float*)d_in[9];
    float* out = (float*)d_out;

    // ---- workspace layout (bytes): ws_size = 268,435,456 (256 MiB).
    // Peak plan = 252,182,528 B.
    //   persist:  [0, 39,845,888)  wkbv | wo_t | kvn_t
    //   kcat:     [39,845,888, 42,205,184)
    //   qcat:     [42,205,184, 117,702,656)  HEAD-MAJOR [h][n][576] ... o1 overlays after s4
    //   scores:   [117,702,656, 251,920,384)  ... early buffers + o2 overlay
    //   inv_g:    [251,920,384, 252,182,528)  (64,1024) fp32 softmax denominators
    const size_t NEED = 252182528ULL;
    if (ws_size < NEED) {
        sentinel_kernel<<<1, 1, 0, stream>>>(out, (float)ws_size);
        return;
    }
    char* ws = (char*)d_ws;
    u16* wkbv   = (u16*)(ws + 0);            // (32,128,512)   4,194,304
    u16* wo_t   = (u16*)(ws + 4194304);      // (4096,4096)   33,554,432
    u16* kvn_t  = (u16*)(ws + 37748736);     // (2,512,1024)   2,097,152
    u16* kcat   = (u16*)(ws + 39845888);     // (2048,576)     2,359,296
    u16* qcat   = (u16*)(ws + 42205184);     // [32 h][2048 n][576] 75,497,472  live s3..s4
    u16* o1     = (u16*)(ws + 42205184);     // [32 h][2048 n][512] overlays qcat (dead after s4)
    u16* scores = (u16*)(ws + 117702656);    // (2,32,1024,1024) 134,217,728  live s4..s5
    // early buffers (all dead before s4) overlay the scores region:
    u16*   xb     = (u16*)(ws + 117702656);  // (2048,4096)       16,777,216
    u16*   wqkv_t = (u16*)(ws + 134479872);  // (2176,4096)       17,825,792  rows 0..1535=wq_a^T,
                                             //   1536..2111=wkv_a^T, 2112..2175 pad (unread)
    u16*   wq_b_t = (u16*)(ws + 152305664);  // (6144,1536)       18,874,368
    u16*   wkbn_t = (u16*)(ws + 171180032);  // (32,512,128)       4,194,304
    float* qk_lat = (float*)(ws + 175374336);// (2048,2176)       17,825,792  cols 0..1535 q_lat,
                                             //   1536..2047 c_kv, 2048..2111 k_pe raw
    u16*   qn     = (u16*)(ws + 193200128);  // (2048,1536)        6,291,456
    u16*   q      = (u16*)(ws + 199491584);  // (2048,6144)       25,165,824 -> ends 224,657,408
    u16*   o2     = (u16*)(ws + 117702656);  // (2048,4096) overlays scores (dead after s5)
    float* inv_g  = (float*)(ws + 251920384);// (64,1024) fp32      262,144

    const dim3 blk(256);
    const float SCALE = 0.0721687836487032f;  // 192^-0.5

    // ---- weight prep: transpose/cast to bf16 (N,K) row-major ----
    transpose_b16<float><<<dim3(48, 128, 1), blk, 0, stream>>>(wq_a, wqkv_t, 4096, 1536, 1536, 4096, 0, 0);
    transpose_b16<float><<<dim3(18, 128, 1), blk, 0, stream>>>(wkva, wqkv_t + (long)1536 * 4096, 4096, 576, 576, 4096, 0, 0);
    transpose_b16<float><<<dim3(192, 48, 1), blk, 0, stream>>>(wq_b, wq_b_t, 1536, 6144, 6144, 1536, 0, 0);
    transpose_b16<float><<<dim3(16, 4, 32), blk, 0, stream>>>(wkvb, wkbn_t, 128, 512, 512, 128, 256 * 512, 512 * 128);
    conv_b16<<<dim3(128, 1, 32), blk, 0, stream>>>(wkvb + 128 * 512, wkbv, 512, 512, 512, 256 * 512, 128 * 512);
    transpose_b16<float><<<dim3(128, 128, 1), blk, 0, stream>>>(wo, wo_t, 4096, 4096, 4096, 4096, 0, 0);
    conv_b16<<<dim3(2048, 1, 1), blk, 0, stream>>>(x, xb, 4096, 4096, 4096, 0, 0);

    // ---- s1 (fused s1a+s1b): qk_lat = xb @ [wq_a | wkv_a]^T : (2048,2176) fp32 ----
    gemm_bt<0, false, false, true><<<dim3(17, 16, 1), blk, 0, stream>>>(
        xb, wqkv_t, qk_lat, 4096, 4096, 4096, 2176, 0, 0, 0, 0, 0, 0, 1.f, nullptr);
    // ---- norms + rope_k + kv transpose ----
    rmsnorm_b16<<<2048, blk, 0, stream>>>(qk_lat, qnw, qn, 1536, 2176, 1536);
    rmsnorm_b16<<<2048, blk, 0, stream>>>(qk_lat + 1536, kvnw, kcat, 512, 2176, 576);
    rope_k_kernel<<<256, blk, 0, stream>>>(qk_lat, fc, kcat);
    transpose_b16<u16><<<dim3(16, 32, 2), blk, 0, stream>>>(kcat, kvn_t, 1024, 512, 576, 1024,
                                                            (long)1024 * 576, (long)512 * 1024);
    // ---- s2: q = qn @ wq_b^T : (2048,6144) bf16 ----
    gemm_bt<1, false, false, true><<<dim3(48, 16, 1), blk, 0, stream>>>(
        qn, wq_b_t, q, 1536, 1536, 1536, 6144, 0, 0, 0, 0, 0, 0, 1.f, nullptr);
    // ---- s3: qcat[h][:, :512] = q_nope @ wkv_b_nope^T per head (z = h), head-major out ----
    gemm_bt<1, false, false, true><<<dim3(4, 16, 32), blk, 0, stream>>>(
        q, wkbn_t, qcat, 128, 6144, 128, 576,
        0, 192, 0, (long)512 * 128, 0, (long)2048 * 576, 1.f, nullptr);
    // ---- rope_q -> qcat[h][:, 512:576] ----
    rope_q_kernel<<<8192, blk, 0, stream>>>(q, fc, qcat);
    // ---- s4: P~ = exp((qcat @ kcat^T)*SCALE + causal mask), per (b,h), z = b*32+h ----
    //      UNNORMALIZED: softmax denominator applied in s5 epilogue via inv_g.
    gemm_bt<2, true, false, true><<<dim3(8, 8, 64), blk, 0, stream>>>(
        qcat, kcat, scores, 576, 576, 576, 1024,
        (long)1024 * 576, (long)2048 * 576, (long)1024 * 576, 0,
        (long)32 * 1048576, 1048576, SCALE, nullptr);
    // ---- row sums -> inv_g (replaces the softmax kernel's 148 MB round-trip) ----
    rowsum_inv<<<dim3(8, 64), blk, 0, stream>>>(scores, inv_g);
    // ---- s5: o1[h][b*1024+s][:] = (P~ @ kv_n) * inv_g[row], K capped at row0+128 ----
    gemm_bt<1, false, true, true, true><<<dim3(4, 8, 64), blk, 0, stream>>>(
        scores, kvn_t, o1, 1024, 1024, 1024, 512,
        (long)32 * 1048576, 1048576, (long)512 * 1024, 0,
        (long)1024 * 512, (long)2048 * 512, 1.f, inv_g);
    // ---- s6: o2[n, h*128+d] = o1 @ wkv_b_v^T per head (z = h), head-major A ----
    gemm_bt<1, false, false, true><<<dim3(1, 16, 32), blk, 0, stream>>>(
        o1, wkbv, o2, 512, 512, 512, 4096,
        0, (long)2048 * 512, 0, (long)128 * 512, 0, 128, 1.f, nullptr);
    // ---- s7: out = o2 @ wo^T : (2048,4096) fp32 ----
    gemm_bt<0, false, false, true><<<dim3(32, 16, 1), blk, 0, stream>>>(
        o2, wo_t, out, 4096, 4096, 4096, 4096, 0, 0, 0, 0, 0, 0, 1.f, nullptr);
    (void)in_sizes; (void)n_in; (void)out_size; (void)d_in;
}